// Round 7
// baseline (436.342 us; speedup 1.0000x reference)
//
#include <hip/hip_runtime.h>

#define N 8192
#define DIN 128
#define DH 48
#define MT 128           // rows per k_gat block (4 waves x 32 rows)
#define KC 64            // j-chunk
#define PSTR (KC + 8)    // f16 row stride: 144 B -> 8B-aligned, low bank aliasing
#define NSPLIT 16
#define JSPAN (N / NSPLIT)   // 512
#define NCHUNK (JSPAN / KC)  // 8
#define ACC_STRIDE 64    // 48 dims + lsum@48 + 15 unused (MFMA N-tile padding)
#define RB 32            // rows per k_mlp block

typedef _Float16 half8 __attribute__((ext_vector_type(8)));
typedef float f32x4 __attribute__((ext_vector_type(4)));

// ---------------- Kernel 1a: Wh = x @ Wgat^T  [8192,128]x[48,128] -> [8192,48]
__global__ __launch_bounds__(256) void k_wh(const float* __restrict__ x,
                                            const float* __restrict__ Wg,
                                            float* __restrict__ Wh) {
    __shared__ float wT[DIN * DH];  // transposed: wT[k*DH + c] = Wg[c*DIN + k]
    int t = threadIdx.x;
    for (int e = t; e < DIN * DH; e += 256) {
        int c = e / DIN, k = e % DIN;
        wT[k * DH + c] = Wg[e];
    }
    __syncthreads();
    int o = blockIdx.x * 256 + t;      // o < 8192*48
    int r = o / DH, c = o % DH;
    const float4* xr = (const float4*)(x + (size_t)r * DIN);
    float acc = 0.f;
    #pragma unroll 8
    for (int k4 = 0; k4 < DIN / 4; ++k4) {
        float4 xv = xr[k4];
        int kb = k4 * 4;
        acc += xv.x * wT[(kb + 0) * DH + c];
        acc += xv.y * wT[(kb + 1) * DH + c];
        acc += xv.z * wT[(kb + 2) * DH + c];
        acc += xv.w * wT[(kb + 3) * DH + c];
    }
    Wh[o] = acc;
}

// ---------------- Kernel 1b: s = Wh @ a^T
__global__ __launch_bounds__(256) void k_s(const float* __restrict__ Wh,
                                           const float* __restrict__ a,
                                           float* __restrict__ s) {
    int r = blockIdx.x * 256 + threadIdx.x;
    const float4* wr = (const float4*)(Wh + (size_t)r * DH);
    const float4* av = (const float4*)a;
    float acc = 0.f;
    #pragma unroll
    for (int k4 = 0; k4 < DH / 4; ++k4) {
        float4 w = wr[k4]; float4 aa = av[k4];
        acc += w.x * aa.x + w.y * aa.y + w.z * aa.z + w.w * aa.w;
    }
    s[r] = acc;
}

// ---------------- Kernel 1c: WhT16[d][j], d in [0,64):
//   d<48 : (f16)Wh[j][d]   (same RTN cast as old wS staging)
//   d=48 : 1.0  (ones column -> lsum)
//   d>48 : 0.0  (MFMA N-tile zero padding)
__global__ __launch_bounds__(256) void k_tr(const float* __restrict__ Wh,
                                            _Float16* __restrict__ WhT16) {
    int o = blockIdx.x * 256 + threadIdx.x;   // o < 64*8192, d-major
    int d = o >> 13, j = o & 8191;
    _Float16 v;
    if (d < DH)       v = (_Float16)Wh[(size_t)j * DH + d];
    else if (d == DH) v = (_Float16)1.0f;
    else              v = (_Float16)0.0f;
    WhT16[o] = v;
}

// ---------------- Kernel 2: fused masked-softmax attention, BARRIER-FREE,
// chunk rotation + WIDE (16 B/lane) adj loads.
//
// Final-round change vs R6: adj loads widened int2 -> int4. Lane decomp
// jq=lane&15 (16 col-groups of 4 ints), rq=lane>>4 (4 rows/instruction):
// one global_load_dwordx4 covers 4 rows x 256 B -> 8 load instructions per
// chunk instead of 16 for the same bytes (the 6.3 TB/s copy ubench is
// 16 B/lane; our 8 B/lane adj stream measured 1.9 TB/s with 95% stall and
// all pipes idle -> request/instruction-rate bound, not bytes/latency/
// occupancy: R4 pipelining, R5 occupancy, R6 rotation all ~flat).
// Phase A packs 4 f16 per thread into one 8-B LDS store (same RTN points
// -> bit-identical result).
__global__ __launch_bounds__(256, 3) void k_gat(const int* __restrict__ adj,
                                                const _Float16* __restrict__ WhT16,
                                                const float* __restrict__ s,
                                                float* __restrict__ accWs) {
    __shared__ _Float16 pS[MT][PSTR];   // A: P[row][j], per-wave 32-row slices
    __shared__ float sRow[MT];
    int t = threadIdx.x;
    int tile = blockIdx.x & 63;        // 64 row tiles of 128
    int split = blockIdx.x >> 6;       // 0..15
    int i0 = tile * MT;
    int jbase = split * JSPAN;

    int lane = t & 63, w = t >> 6;
    int ln16 = lane & 15, kq = lane >> 4;   // MFMA lane decomposition
    int jq = lane & 15, rq = lane >> 4;     // phase A: col-quad, row-in-quad

    int rw = w * 32;                        // wave's first row within tile
    int phase = (tile + 2 * w) & (NCHUNK - 1);   // per-wave chunk rotation
    const int* adjBase = adj + (size_t)(i0 + rw + rq) * N + jbase + 4 * jq;

    // per-wave sRow staging (same-wave DS is in-order; lgkmcnt covers it)
    if (lane < 32) sRow[rw + lane] = s[i0 + rw + lane];

    // ---- prologue: first-chunk prefetch (adj rows + s chunk) into registers
    int chunk0 = phase;
    int4 adjR[8];
    #pragma unroll
    for (int it = 0; it < 8; ++it)
        adjR[it] = *(const int4*)(adjBase + (size_t)(4 * it) * N + chunk0 * KC);
    float4 sjR = *(const float4*)(s + jbase + chunk0 * KC + 4 * jq);

    f32x4 acc[2][4];
    #pragma unroll
    for (int a0 = 0; a0 < 2; ++a0)
        #pragma unroll
        for (int b0 = 0; b0 < 4; ++b0) acc[a0][b0] = (f32x4){0.f, 0.f, 0.f, 0.f};

    for (int cc = 0; cc < NCHUNK; ++cc) {
        int chunk = (cc + phase) & (NCHUNK - 1);
        int j0 = jbase + chunk * KC;
        // ---- B fragments for this chunk (oldest vmcnt slots: the MFMA's
        //      wait on these leaves the younger adjR' prefetch in flight)
        half8 bf[2][4];
        #pragma unroll
        for (int kt = 0; kt < 2; ++kt)
            #pragma unroll
            for (int nt = 0; nt < 4; ++nt)
                bf[kt][nt] = *(const half8*)&WhT16[(size_t)(nt * 16 + ln16) * N
                                                  + j0 + kt * 32 + kq * 8];
        // ---- phase A: p (f16) for wave's 32 rows x 64 j from prefetched adjR
        {
            float4 sj = sjR;
            #pragma unroll
            for (int it = 0; it < 8; ++it) {
                int r = rw + 4 * it + rq;
                int4 av = adjR[it];
                float sr = sRow[r];
                float e0 = sr + sj.x, e1 = sr + sj.y;
                float e2 = sr + sj.z, e3 = sr + sj.w;
                e0 = fmaxf(e0, 0.2f * e0);              // LeakyReLU(0.2)
                e1 = fmaxf(e1, 0.2f * e1);
                e2 = fmaxf(e2, 0.2f * e2);
                e3 = fmaxf(e3, 0.2f * e3);
                float p0 = av.x ? __expf(e0) : 0.f;     // masked -> exact 0
                float p1 = av.y ? __expf(e1) : 0.f;
                float p2 = av.z ? __expf(e2) : 0.f;
                float p3 = av.w ? __expf(e3) : 0.f;
                union { _Float16 h[4]; double d; } pk;
                pk.h[0] = (_Float16)p0;                 // RTN (same as R6)
                pk.h[1] = (_Float16)p1;
                pk.h[2] = (_Float16)p2;
                pk.h[3] = (_Float16)p3;
                *(double*)&pS[r][4 * jq] = pk.d;        // 8-B aligned store
            }
        }
        // ---- issue next-chunk prefetch; sched_barrier pins the issue point
        if (cc < NCHUNK - 1) {
            int nchunk = (cc + 1 + phase) & (NCHUNK - 1);
            #pragma unroll
            for (int it = 0; it < 8; ++it)
                adjR[it] = *(const int4*)(adjBase + (size_t)(4 * it) * N
                                          + nchunk * KC);
            sjR = *(const float4*)(s + jbase + nchunk * KC + 4 * jq);
        }
        __builtin_amdgcn_sched_barrier(0);
        // ---- MFMA MAC (wave-internal pS: compiler inserts lgkmcnt, no barrier)
        __builtin_amdgcn_s_setprio(1);
        #pragma unroll
        for (int kt = 0; kt < 2; ++kt) {
            const int kk = kt * 32 + kq * 8;
            #pragma unroll
            for (int mtl = 0; mtl < 2; ++mtl) {
                half8 a = *(const half8*)&pS[rw + mtl * 16 + ln16][kk];
                #pragma unroll
                for (int nt = 0; nt < 4; ++nt)
                    acc[mtl][nt] = __builtin_amdgcn_mfma_f32_16x16x32_f16(
                        a, bf[kt][nt], acc[mtl][nt], 0, 0, 0);
            }
        }
        __builtin_amdgcn_s_setprio(0);
    }
    // ---- epilogue: C/D layout col=lane&15, row=kq*4+reg
    size_t rbase = (size_t)split * N + i0;
    #pragma unroll
    for (int mtl = 0; mtl < 2; ++mtl) {
        #pragma unroll
        for (int nt = 0; nt < 4; ++nt) {
            int col = nt * 16 + ln16;
            if (nt == 3 && ln16 != 0) continue;   // only col 48 (lsum) useful
            #pragma unroll
            for (int reg = 0; reg < 4; ++reg) {
                int row = rw + mtl * 16 + kq * 4 + reg;
                accWs[(rbase + row) * ACC_STRIDE + col] = acc[mtl][nt][reg];
            }
        }
    }
}

// ---------------- Kernel 3: reduce splits + LayerNorm + MFMA MLP 48->256->128->32
__global__ __launch_bounds__(256) void k_mlp(const float* __restrict__ accWs,
                                             const float* __restrict__ gamma,
                                             const float* __restrict__ beta,
                                             const float* __restrict__ W1, const float* __restrict__ b1,
                                             const float* __restrict__ W2, const float* __restrict__ b2,
                                             const float* __restrict__ W3, const float* __restrict__ b3,
                                             float* __restrict__ out) {
    __shared__ float hacc[RB * 49];
    __shared__ _Float16 hN[RB * 72];    // [32][72] f16, cols 48..71 zero (K pad)
    __shared__ _Float16 h1[RB * 264];   // [32][264] f16
    __shared__ float h2[RB * 132];      // [32][132] f32
    int t = threadIdx.x;
    int r0 = blockIdx.x * RB;
    int lane = t & 63, w = t >> 6;
    int ln16 = lane & 15, kq = lane >> 4;

    // reduce K-split partials (d: 0..47 dims, 48 = lsum)
    for (int e = t; e < RB * 49; e += 256) {
        int r = e / 49, d = e % 49;
        size_t base = (size_t)(r0 + r) * ACC_STRIDE + d;
        float v = 0.f;
        #pragma unroll
        for (int sp = 0; sp < NSPLIT; ++sp)
            v += accWs[(size_t)sp * N * ACC_STRIDE + base];
        hacc[e] = v;
    }
    __syncthreads();

    // LayerNorm (two-pass), h' = acc / l ; store f16 for MFMA A-operand
    if (t < RB) {
        float invl = 1.f / hacc[t * 49 + 48];
        float sum = 0.f;
        for (int d = 0; d < DH; ++d) sum += hacc[t * 49 + d];
        float mean = sum * invl * (1.f / DH);
        float var = 0.f;
        for (int d = 0; d < DH; ++d) {
            float dv = hacc[t * 49 + d] * invl - mean;
            var += dv * dv;
        }
        var *= (1.f / DH);
        float rs = rsqrtf(var + 1e-5f);
        for (int d = 0; d < DH; ++d) {
            float hv = (hacc[t * 49 + d] * invl - mean) * rs;
            hN[t * 72 + d] = (_Float16)(hv * gamma[d] + beta[d]);
        }
        for (int d = DH; d < 72; ++d) hN[t * 72 + d] = (_Float16)0.f;
    }
    __syncthreads();

    // MLP1 (MFMA): M=32, N=256, K=48 padded to 64. wave w owns N-tiles w*4..w*4+3
    {
        f32x4 acc1[2][4];
        #pragma unroll
        for (int mt = 0; mt < 2; ++mt)
            #pragma unroll
            for (int nt = 0; nt < 4; ++nt) acc1[mt][nt] = (f32x4){0.f, 0.f, 0.f, 0.f};
        #pragma unroll
        for (int kt = 0; kt < 2; ++kt) {
            int k = kt * 32 + kq * 8;
            half8 a[2];
            #pragma unroll
            for (int mt = 0; mt < 2; ++mt)
                a[mt] = *(const half8*)&hN[(mt * 16 + ln16) * 72 + k];
            #pragma unroll
            for (int ntl = 0; ntl < 4; ++ntl) {
                int n = (w * 4 + ntl) * 16 + ln16;
                half8 b;
                #pragma unroll
                for (int i = 0; i < 8; ++i) b[i] = (_Float16)0.f;
                if (k < DH) {   // k in {0,8,16,24,32,40}; >=48 stays zero
                    float4 lo = *(const float4*)(W1 + n * DH + k);
                    float4 hi = *(const float4*)(W1 + n * DH + k + 4);
                    b[0] = (_Float16)lo.x; b[1] = (_Float16)lo.y;
                    b[2] = (_Float16)lo.z; b[3] = (_Float16)lo.w;
                    b[4] = (_Float16)hi.x; b[5] = (_Float16)hi.y;
                    b[6] = (_Float16)hi.z; b[7] = (_Float16)hi.w;
                }
                #pragma unroll
                for (int mt = 0; mt < 2; ++mt)
                    acc1[mt][ntl] = __builtin_amdgcn_mfma_f32_16x16x32_f16(
                        a[mt], b, acc1[mt][ntl], 0, 0, 0);
            }
        }
        #pragma unroll
        for (int mt = 0; mt < 2; ++mt)
            #pragma unroll
            for (int ntl = 0; ntl < 4; ++ntl) {
                int col = (w * 4 + ntl) * 16 + ln16;
                float bias = b1[col];
                #pragma unroll
                for (int reg = 0; reg < 4; ++reg) {
                    int row = mt * 16 + kq * 4 + reg;
                    float v = acc1[mt][ntl][reg] + bias;
                    h1[row * 264 + col] = (_Float16)fmaxf(v, 0.f);
                }
            }
    }
    __syncthreads();

    // MLP2 (MFMA): M=32, N=128, K=256. wave w owns N-tiles w*2, w*2+1
    {
        f32x4 acc2[2][2];
        #pragma unroll
        for (int mt = 0; mt < 2; ++mt)
            #pragma unroll
            for (int nt = 0; nt < 2; ++nt) acc2[mt][nt] = (f32x4){0.f, 0.f, 0.f, 0.f};
        #pragma unroll
        for (int kt = 0; kt < 8; ++kt) {
            int k = kt * 32 + kq * 8;
            half8 a[2];
            #pragma unroll
            for (int mt = 0; mt < 2; ++mt)
                a[mt] = *(const half8*)&h1[(mt * 16 + ln16) * 264 + k];
            #pragma unroll
            for (int ntl = 0; ntl < 2; ++ntl) {
                int n = (w * 2 + ntl) * 16 + ln16;
                float4 lo = *(const float4*)(W2 + n * 256 + k);
                float4 hi = *(const float4*)(W2 + n * 256 + k + 4);
                half8 b;
                b[0] = (_Float16)lo.x; b[1] = (_Float16)lo.y;
                b[2] = (_Float16)lo.z; b[3] = (_Float16)lo.w;
                b[4] = (_Float16)hi.x; b[5] = (_Float16)hi.y;
                b[6] = (_Float16)hi.z; b[7] = (_Float16)hi.w;
                #pragma unroll
                for (int mt = 0; mt < 2; ++mt)
                    acc2[mt][ntl] = __builtin_amdgcn_mfma_f32_16x16x32_f16(
                        a[mt], b, acc2[mt][ntl], 0, 0, 0);
            }
        }
        #pragma unroll
        for (int mt = 0; mt < 2; ++mt)
            #pragma unroll
            for (int ntl = 0; ntl < 2; ++ntl) {
                int col = (w * 2 + ntl) * 16 + ln16;
                float bias = b2[col];
                #pragma unroll
                for (int reg = 0; reg < 4; ++reg) {
                    int row = mt * 16 + kq * 4 + reg;
                    h2[row * 132 + col] = fmaxf(acc2[mt][ntl][reg] + bias, 0.f);
                }
            }
    }
    __syncthreads();

    // MLP3: 128 -> 32 (scalar; small)
    {
        int c = t & 31;
        int g = t >> 5;
        int rb = g * 4;
        float acc[4];
        float bias = b3[c];
        #pragma unroll
        for (int r = 0; r < 4; ++r) acc[r] = bias;
        const float4* wrow = (const float4*)(W3 + c * 128);
        for (int k4 = 0; k4 < 32; ++k4) {
            float4 wv = wrow[k4];
            #pragma unroll
            for (int r = 0; r < 4; ++r) {
                const float4 hv = *(const float4*)(&h2[(rb + r) * 132 + k4 * 4]);
                acc[r] += wv.x * hv.x + wv.y * hv.y + wv.z * hv.z + wv.w * hv.w;
            }
        }
        #pragma unroll
        for (int r = 0; r < 4; ++r)
            out[(size_t)(r0 + rb + r) * 32 + c] = acc[r];
    }
}

extern "C" void kernel_launch(void* const* d_in, const int* in_sizes, int n_in,
                              void* d_out, int out_size, void* d_ws, size_t ws_size,
                              hipStream_t stream) {
    const float* x     = (const float*)d_in[0];
    const int*   adj   = (const int*)d_in[1];
    const float* Wg    = (const float*)d_in[2];
    const float* a     = (const float*)d_in[3];
    const float* gamma = (const float*)d_in[4];
    const float* beta  = (const float*)d_in[5];
    const float* W1    = (const float*)d_in[6];
    const float* b1    = (const float*)d_in[7];
    const float* W2    = (const float*)d_in[8];
    const float* b2    = (const float*)d_in[9];
    const float* W3    = (const float*)d_in[10];
    const float* b3    = (const float*)d_in[11];
    float* out = (float*)d_out;

    float* ws = (float*)d_ws;
    float* Wh       = ws;                          // 8192*48 f32
    float* s        = ws + (size_t)N * DH;         // 8192 f32
    _Float16* WhT16 = (_Float16*)(s + N);          // 64*8192 f16 (16B-aligned)
    float* accWs    = (float*)((char*)WhT16 + (size_t)64 * N * sizeof(_Float16));
                                                   // NSPLIT*8192*64 f32 = 33.5 MB

    k_wh<<<N * DH / 256, 256, 0, stream>>>(x, Wg, Wh);
    k_s<<<N / 256, 256, 0, stream>>>(Wh, a, s);
    k_tr<<<64 * N / 256, 256, 0, stream>>>(Wh, WhT16);
    k_gat<<<64 * NSPLIT, 256, 0, stream>>>(adj, WhT16, s, accWs);
    k_mlp<<<N / RB, 256, 0, stream>>>(accWs, gamma, beta, W1, b1, W2, b2, W3, b3, out);
}